// Round 14
// baseline (653.279 us; speedup 1.0000x reference)
//
#include <hip/hip_runtime.h>

// VectorQuantizer: X [16384][128] f32, E [128][8192] f32
// out (f32 flat): quantized [16384*128], encodings [16384*8192], indices [16384], loss [1]
// R14: wave-role specialization. Waves 0-1 = compute (NO global mem ops in loop),
// wave 2 = stage (loads+ds_writes, NO stores), wave 3 = fill (pure NT store stream).
// Rationale: in-order issue means a wave stalled on store backpressure issues
// NOTHING; R5-R13 all had stores in every wave's stream -> compute serialized
// behind the 537MB fill. Role split gives backpressure a free victim (wave 3).
#define D 128
#define K 8192
#define N 16384
#define BM 32                 // rows per block (grid 512 -> 2 blocks/CU)
#define BN 128                // codebook cols per chunk
#define NCH (K / BN)          // 64
#define GRP 4                 // chunks per gate-group
#define THREADS 256
#define CAND_CAP 1024
#define DELTA 0.5f
#define RMIN_INIT 0xFF800000u // fsort(+inf); NOT 0xFFFFFFFF (decodes to NaN)

typedef __attribute__((ext_vector_type(4))) float f32x4;
typedef __attribute__((ext_vector_type(16))) float f32x16;
typedef __attribute__((ext_vector_type(8))) short short8;

__device__ __forceinline__ unsigned short f2bf(float f) {
    unsigned int b = __float_as_uint(f);
    return (unsigned short)((b + 0x7FFFu + ((b >> 16) & 1u)) >> 16);
}
__device__ __forceinline__ unsigned int fsort(float f) {
    unsigned int b = __float_as_uint(f);
    return b ^ ((unsigned int)((int)b >> 31) | 0x80000000u);
}
__device__ __forceinline__ float funsort(unsigned int u) {
    return __uint_as_float((u & 0x80000000u) ? (u ^ 0x80000000u) : ~u);
}

__device__ __forceinline__ void lds_barrier() {
    asm volatile("s_waitcnt lgkmcnt(0)" ::: "memory");
    __builtin_amdgcn_s_barrier();
}

// ---- prep: E -> bf16 transposed e1t[k][d], augt[k][8]={en_hi,en_lo,0...},
//      f32 transposed e2t[k][d], enorm ----
__global__ __launch_bounds__(256) void prep_kernel(const float* __restrict__ E,
        unsigned short* __restrict__ e1t, unsigned short* __restrict__ augt,
        float* __restrict__ e2t, float* __restrict__ enorm) {
    __shared__ float esum[8][32];
    const int t = threadIdx.x;
    const int kl = t & 31, dg = t >> 5;
    const int k = blockIdx.x * 32 + kl;
    float s = 0.f;
    __align__(16) unsigned short tmpb[16];
    __align__(16) float tmpf[16];
#pragma unroll
    for (int j = 0; j < 16; ++j) {
        float v = E[(size_t)(dg * 16 + j) * K + k];
        s += v * v;
        tmpb[j] = f2bf(v);
        tmpf[j] = v;
    }
    *(f32x4*)(e1t + (size_t)k * D + dg * 16) = *(const f32x4*)tmpb;
    *(f32x4*)(e1t + (size_t)k * D + dg * 16 + 8) = *(const f32x4*)(tmpb + 8);
    if (e2t) {
#pragma unroll
        for (int q = 0; q < 4; ++q)
            *(f32x4*)(e2t + (size_t)k * D + dg * 16 + 4 * q) = *(const f32x4*)(tmpf + 4 * q);
    }
    esum[dg][kl] = s;
    __syncthreads();
    if (t < 32) {
        float e = 0.f;
#pragma unroll
        for (int g = 0; g < 8; ++g) e += esum[g][t];
        const int kk = blockIdx.x * 32 + t;
        enorm[kk] = e;
        unsigned short hi = f2bf(e);
        float hif = __uint_as_float((unsigned int)hi << 16);
        unsigned short lo = f2bf(e - hif);
        __align__(16) unsigned short av[8] = {hi, lo, 0, 0, 0, 0, 0, 0};
        *(f32x4*)(augt + (size_t)kk * 8) = *(const f32x4*)av;
    }
}

template<int E2T>
__global__ __launch_bounds__(THREADS, 2) void main_kernel(
        const float* __restrict__ X, const float* __restrict__ E,
        const unsigned short* __restrict__ e1t, const unsigned short* __restrict__ augt,
        const float* __restrict__ e2t, const float* __restrict__ enorm,
        float* __restrict__ out, float* __restrict__ partials) {
    __shared__ __align__(16) unsigned short b_s[2][BN * D];   // 64 KB, XOR-swizzled
    __shared__ __align__(16) unsigned short aug_s[2][BN * 8]; // 4 KB
    __shared__ unsigned long long cand[CAND_CAP];             // 8 KB
    __shared__ unsigned long long best[BM];
    __shared__ unsigned int rmin[BM];
    __shared__ int candn;
    // ~76.4 KB -> 2 blocks/CU

    const int t = threadIdx.x;
    const int wid = t >> 6, l = t & 63;
    const int l31 = l & 31, lh = l >> 5;
    const int rowbase = blockIdx.x * BM;

    float* qout = out;
    float* enc = out + (size_t)N * D;
    float* idxout = enc + (size_t)N * K;
    float* stripe = enc + (size_t)rowbase * K;   // block's 1 MB contiguous fill region

    if (t < BM) { rmin[t] = RMIN_INIT; best[t] = ~0ull; }
    if (t == 0) candn = 0;

    // ---- compute waves' A fragments: bf16(-2x) for the block's 32 rows ----
    short8 afr[8];
    short8 a_aug;
    if (wid < 2) {
        const int row = rowbase + l31;
#pragma unroll
        for (int ks = 0; ks < 8; ++ks) {
            const float* xp = X + (size_t)row * D + ks * 16 + lh * 8;
            f32x4 v0 = *(const f32x4*)xp;
            f32x4 v1 = *(const f32x4*)(xp + 4);
            short8 a;
            a[0] = (short)f2bf(-2.f * v0[0]); a[1] = (short)f2bf(-2.f * v0[1]);
            a[2] = (short)f2bf(-2.f * v0[2]); a[3] = (short)f2bf(-2.f * v0[3]);
            a[4] = (short)f2bf(-2.f * v1[0]); a[5] = (short)f2bf(-2.f * v1[1]);
            a[6] = (short)f2bf(-2.f * v1[2]); a[7] = (short)f2bf(-2.f * v1[3]);
            afr[ks] = a;
        }
        const short one = (short)0x3F80;  // bf16 1.0
        a_aug[0] = (lh == 0) ? one : (short)0;
        a_aug[1] = (lh == 0) ? one : (short)0;
        a_aug[2] = 0; a_aug[3] = 0; a_aug[4] = 0;
        a_aug[5] = 0; a_aug[6] = 0; a_aug[7] = 0;
    }

    // ---- stage wave prologue: chunk 0 into buf 0 ----
    if (wid == 2) {
#pragma unroll
        for (int b = 0; b < 4; ++b) {
            f32x4 v[8];
#pragma unroll
            for (int j = 0; j < 8; ++j)
                v[j] = ((const f32x4*)e1t)[l + 64 * (b * 8 + j)];
#pragma unroll
            for (int j = 0; j < 8; ++j) {
                int unit = l + 64 * (b * 8 + j);
                int c = unit >> 4, slot = unit & 15;
                *(f32x4*)((char*)&b_s[0][0] + c * 256 + ((slot ^ (c & 15)) << 4)) = v[j];
            }
        }
        f32x4 a0 = ((const f32x4*)augt)[l];
        f32x4 a1 = ((const f32x4*)augt)[l + 64];
        *(f32x4*)((char*)&aug_s[0][0] + l * 16) = a0;
        *(f32x4*)((char*)&aug_s[0][0] + (l + 64) * 16) = a1;
    }

    const f32x4 z = {0.f, 0.f, 0.f, 0.f};
    int cur = 0;
    for (int cg = 0; cg < NCH / GRP; ++cg) {
        f32x16 dsv[GRP][2];   // compute only; compile-time indexed
#pragma unroll
        for (int g = 0; g < GRP; ++g) {
            const int ch = cg * GRP + g;
            lds_barrier();   // publish buf[cur] (chunk ch); prev reads done

            if (wid < 2) {
                // ---- COMPUTE: 2 sub-tiles, pure LDS+MFMA ----
#pragma unroll
                for (int sp = 0; sp < 2; ++sp) {
                    const int c = (wid * 2 + sp) * 32 + l31;
                    f32x16 acc;
#pragma unroll
                    for (int r = 0; r < 16; ++r) acc[r] = 0.f;
#pragma unroll
                    for (int ks = 0; ks < 8; ++ks) {
                        const int slot = ks * 2 + lh;
                        short8 bf = *(const short8*)((const char*)&b_s[cur][0] + c * 256 +
                                                     ((slot ^ (c & 15)) << 4));
                        acc = __builtin_amdgcn_mfma_f32_32x32x16_bf16(afr[ks], bf, acc, 0, 0, 0);
                    }
                    short8 ba = {0, 0, 0, 0, 0, 0, 0, 0};
                    if (lh == 0) ba = *(const short8*)((const char*)&aug_s[cur][0] + c * 16);
                    acc = __builtin_amdgcn_mfma_f32_32x32x16_bf16(a_aug, ba, acc, 0, 0, 0);
#pragma unroll
                    for (int r = 0; r < 16; ++r) dsv[g][sp][r] = acc[r];
                }
            } else if (wid == 2) {
                // ---- STAGE: load chunk ch+1, ds_write into buf[cur^1] ----
                if (ch + 1 < NCH) {
                    const f32x4* gs = (const f32x4*)(e1t + (size_t)(ch + 1) * BN * D);
#pragma unroll
                    for (int b = 0; b < 4; ++b) {
                        f32x4 v[8];
#pragma unroll
                        for (int j = 0; j < 8; ++j)
                            v[j] = gs[l + 64 * (b * 8 + j)];
#pragma unroll
                        for (int j = 0; j < 8; ++j) {
                            int unit = l + 64 * (b * 8 + j);
                            int c = unit >> 4, slot = unit & 15;
                            *(f32x4*)((char*)&b_s[cur ^ 1][0] + c * 256 +
                                      ((slot ^ (c & 15)) << 4)) = v[j];
                        }
                    }
                    const f32x4* ga = (const f32x4*)(augt + (size_t)(ch + 1) * BN * 8);
                    f32x4 a0 = ga[l];
                    f32x4 a1 = ga[l + 64];
                    *(f32x4*)((char*)&aug_s[cur ^ 1][0] + l * 16) = a0;
                    *(f32x4*)((char*)&aug_s[cur ^ 1][0] + (l + 64) * 16) = a1;
                }
            } else {
                // ---- FILL: pure NT store stream, 16 KB slice of the stripe ----
                float* base = stripe + (size_t)ch * 4096;
#pragma unroll
                for (int j = 0; j < 16; ++j)
                    __builtin_nontemporal_store(z, (f32x4*)(base + j * 256 + l * 4));
            }
            cur ^= 1;
        }

        if (wid < 2) {
            // ---- per-group gate: one shuffle reduce per GRP chunks ----
            float lmin[16];
#pragma unroll
            for (int r = 0; r < 16; ++r) {
                float m0 = fminf(dsv[0][0][r], dsv[0][1][r]);
                float m1 = fminf(dsv[1][0][r], dsv[1][1][r]);
                float m2 = fminf(dsv[2][0][r], dsv[2][1][r]);
                float m3 = fminf(dsv[3][0][r], dsv[3][1][r]);
                lmin[r] = fminf(fminf(m0, m1), fminf(m2, m3));
            }
#pragma unroll
            for (int m = 1; m <= 16; m <<= 1)
#pragma unroll
                for (int r = 0; r < 16; ++r)
                    lmin[r] = fminf(lmin[r], __shfl_xor(lmin[r], m, 64));

            float thrv[16];
#pragma unroll
            for (int q = 0; q < 4; ++q) {
                const int base = 8 * q + 4 * lh;
                uint4 rv = *(const uint4*)&rmin[base];
                thrv[4 * q + 0] = funsort(rv.x);
                thrv[4 * q + 1] = funsort(rv.y);
                thrv[4 * q + 2] = funsort(rv.z);
                thrv[4 * q + 3] = funsort(rv.w);
            }

#pragma unroll
            for (int r = 0; r < 16; ++r) {
                const int ro = (r & 3) + 8 * (r >> 2) + 4 * lh;
                const float te = fminf(thrv[r], lmin[r]) + DELTA;
#pragma unroll
                for (int g = 0; g < GRP; ++g)
#pragma unroll
                    for (int sp = 0; sp < 2; ++sp) {
                        if (dsv[g][sp][r] < te) {
                            const int col = (cg * GRP + g) * BN + (wid * 2 + sp) * 32 + l31;
                            int ci = atomicAdd(&candn, 1);
                            if (ci < CAND_CAP)
                                cand[ci] = ((unsigned long long)fsort(dsv[g][sp][r]) << 32) |
                                           ((unsigned long long)ro << 13) | (unsigned)col;
                        }
                    }
                if (l31 == 0 && lmin[r] < thrv[r])
                    atomicMin(&rmin[ro], fsort(lmin[r]));
            }
        }
    }

    __syncthreads();   // FULL drain: fill stores complete; rmin/cand final

    // ---- exact f32 verification of surviving candidates (all 4 waves) ----
    {
        int n = candn; if (n > CAND_CAP) n = CAND_CAP;
        for (int i = wid; i < n; i += 4) {
            const unsigned long long e = cand[i];
            const float dta = funsort((unsigned int)(e >> 32));
            const int ro = (int)((e >> 13) & 63u);
            const int col = (int)(e & 8191u);
            if (dta < funsort(rmin[ro]) + DELTA) {
                const int row = rowbase + ro;
                float x0 = X[(size_t)row * D + l];
                float x1 = X[(size_t)row * D + 64 + l];
                float e0, e1;
                if (E2T) {
                    e0 = e2t[(size_t)col * D + l];
                    e1 = e2t[(size_t)col * D + 64 + l];
                } else {
                    e0 = E[(size_t)l * K + col];
                    e1 = E[(size_t)(l + 64) * K + col];
                }
                float s = x0 * e0 + x1 * e1;
#pragma unroll
                for (int m = 1; m <= 32; m <<= 1) s += __shfl_xor(s, m, 64);
                if (l == 0) {
                    float dtx = enorm[col] - 2.f * s;
                    atomicMin(&best[ro],
                        ((unsigned long long)fsort(dtx) << 32) | (unsigned)col);
                }
            }
        }
    }
    __syncthreads();

    // ---- outputs: indices, one-hot scatter, quantized, loss partial ----
    float* red = (float*)&b_s[0][0];   // b_s dead after loop
    if (t < BM) {
        const int k = (int)(best[t] & 8191ull);
        idxout[rowbase + t] = (float)k;
        __builtin_nontemporal_store(1.0f, &enc[(size_t)(rowbase + t) * K + k]);
    }

    const int rr = t >> 3, sL = t & 7;
    const int row = rowbase + rr;
    const int kb = (int)(best[rr] & 8191ull);
    float part = 0.f;
#pragma unroll
    for (int j = 0; j < 4; ++j) {
        const int d0 = sL * 16 + 4 * j;
        f32x4 xv = *(const f32x4*)(X + (size_t)row * D + d0);
        f32x4 ev;
        if (E2T) {
            ev = *(const f32x4*)(e2t + (size_t)kb * D + d0);
        } else {
#pragma unroll
            for (int u = 0; u < 4; ++u) ev[u] = E[(size_t)(d0 + u) * K + kb];
        }
        f32x4 qv;
#pragma unroll
        for (int u = 0; u < 4; ++u) {
            float df = ev[u] - xv[u];
            qv[u] = xv[u] + df;
            part += df * df;
        }
        *(f32x4*)(qout + (size_t)row * D + d0) = qv;
    }
    red[t] = part;
    __syncthreads();
#pragma unroll
    for (int off = THREADS / 2; off > 0; off >>= 1) {
        if (t < off) red[t] += red[t + off];
        __syncthreads();
    }
    if (t == 0) partials[blockIdx.x] = red[0];
}

__global__ __launch_bounds__(256) void loss_kernel(const float* __restrict__ partials,
                                                   float* __restrict__ out) {
    __shared__ float red[256];
    const int t = threadIdx.x;
    red[t] = partials[t] + partials[t + 256];
    __syncthreads();
    for (int off = 128; off > 0; off >>= 1) {
        if (t < off) red[t] += red[t + off];
        __syncthreads();
    }
    if (t == 0) {
        float mean = red[0] / (float)((size_t)N * D);
        out[(size_t)N * D + (size_t)N * K + N] = mean + 0.25f * mean;
    }
}

extern "C" void kernel_launch(void* const* d_in, const int* in_sizes, int n_in,
                              void* d_out, int out_size, void* d_ws, size_t ws_size,
                              hipStream_t stream) {
    const float* X = (const float*)d_in[0];
    const float* E = (const float*)d_in[1];
    float* out = (float*)d_out;
    char* ws = (char*)d_ws;

    const size_t E1T_B = (size_t)K * D * 2;          // 2 MB
    const size_t AUG_B = (size_t)K * 8 * 2;          // 128 KB
    const size_t E2T_B = (size_t)K * D * 4;          // 4 MB
    const bool use_e2t = ws_size >= E1T_B + AUG_B + E2T_B + 64 * 1024;

    unsigned short* e1t = (unsigned short*)ws;
    unsigned short* augt = (unsigned short*)(ws + E1T_B);
    float* e2t; float* enorm; float* partials;
    if (use_e2t) {
        e2t = (float*)(ws + E1T_B + AUG_B);
        enorm = (float*)(ws + E1T_B + AUG_B + E2T_B);
        partials = enorm + K;
    } else {
        e2t = nullptr;
        enorm = (float*)(ws + E1T_B + AUG_B);
        partials = enorm + K;
    }

    hipLaunchKernelGGL(prep_kernel, dim3(K / 32), dim3(256), 0, stream,
                       E, e1t, augt, e2t, enorm);
    if (use_e2t)
        hipLaunchKernelGGL((main_kernel<1>), dim3(N / BM), dim3(THREADS), 0, stream,
                           X, E, e1t, augt, e2t, enorm, out, partials);
    else
        hipLaunchKernelGGL((main_kernel<0>), dim3(N / BM), dim3(THREADS), 0, stream,
                           X, E, e1t, augt, e2t, enorm, out, partials);
    hipLaunchKernelGGL(loss_kernel, dim3(1), dim3(256), 0, stream, partials, out);
}

// Round 15
// 220.985 us; speedup vs baseline: 2.9562x; 2.9562x over previous
//
#include <hip/hip_runtime.h>

// VectorQuantizer: X [16384][128] f32, E [128][8192] f32
// out (f32 flat): quantized [16384*128], encodings [16384*8192], indices [16384], loss [1]
// R15: empirical law from R10-R14: store BW ~ 1.7 GB/s per STORING WAVE.
// Lever 1: dedicated pure-store fill kernel (fillBuffer-like) zeroes cols [0,5120).
// Lever 2: main = 512 thr (8 waves all storing) x 2 blocks/CU = 16 storing waves/CU,
// no LDS staging (direct-L2 B-frags), rolling-threshold gate (butterfly @ tile 0 only).
#define D 128
#define K 8192
#define N 16384
#define BM 32                 // rows per block (grid 512 -> 2 blocks/CU)
#define TILES 32              // 256-col stripes; wave's tile = 32 cols
#define FCOLS 5120            // cols filled by fill_kernel; main fills [FCOLS, K)
#define THREADS 512
#define CAND_CAP 2048
#define DELTA 0.5f
#define RMIN_INIT 0xFF800000u // fsort(+inf); NOT 0xFFFFFFFF (decodes to NaN)

typedef __attribute__((ext_vector_type(4))) float f32x4;
typedef __attribute__((ext_vector_type(16))) float f32x16;
typedef __attribute__((ext_vector_type(8))) short short8;

__device__ __forceinline__ unsigned short f2bf(float f) {
    unsigned int b = __float_as_uint(f);
    return (unsigned short)((b + 0x7FFFu + ((b >> 16) & 1u)) >> 16);
}
__device__ __forceinline__ unsigned int fsort(float f) {
    unsigned int b = __float_as_uint(f);
    return b ^ ((unsigned int)((int)b >> 31) | 0x80000000u);
}
__device__ __forceinline__ float funsort(unsigned int u) {
    return __uint_as_float((u & 0x80000000u) ? (u ^ 0x80000000u) : ~u);
}

// ---- prep: E -> bf16 transposed e1t[k][d], f32 transposed e2t[k][d], enorm ----
__global__ __launch_bounds__(256) void prep_kernel(const float* __restrict__ E,
        unsigned short* __restrict__ e1t, float* __restrict__ e2t,
        float* __restrict__ enorm) {
    __shared__ float esum[8][32];
    const int t = threadIdx.x;
    const int kl = t & 31, dg = t >> 5;
    const int k = blockIdx.x * 32 + kl;
    float s = 0.f;
    __align__(16) unsigned short tmpb[16];
    __align__(16) float tmpf[16];
#pragma unroll
    for (int j = 0; j < 16; ++j) {
        float v = E[(size_t)(dg * 16 + j) * K + k];
        s += v * v;
        tmpb[j] = f2bf(v);
        tmpf[j] = v;
    }
    *(f32x4*)(e1t + (size_t)k * D + dg * 16) = *(const f32x4*)tmpb;
    *(f32x4*)(e1t + (size_t)k * D + dg * 16 + 8) = *(const f32x4*)(tmpb + 8);
    if (e2t) {
#pragma unroll
        for (int q = 0; q < 4; ++q)
            *(f32x4*)(e2t + (size_t)k * D + dg * 16 + 4 * q) = *(const f32x4*)(tmpf + 4 * q);
    }
    esum[dg][kl] = s;
    __syncthreads();
    if (t < 32) {
        float e = 0.f;
#pragma unroll
        for (int g = 0; g < 8; ++g) e += esum[g][t];
        enorm[blockIdx.x * 32 + t] = e;
    }
}

// ---- fill: pure-store kernel, zeroes enc[:, 0:FCOLS) (fillBuffer regime) ----
__global__ __launch_bounds__(256) void fill_kernel(float* __restrict__ enc) {
    const unsigned int u0 = blockIdx.x * 256 + threadIdx.x;
    const unsigned int stride = 4096 * 256;          // grid is 4096 blocks
    const f32x4 z = {0.f, 0.f, 0.f, 0.f};
#pragma unroll
    for (int i = 0; i < 20; ++i) {                   // 4096*256*20 = N*(FCOLS/4) exactly
        unsigned int u = u0 + (unsigned int)i * stride;
        unsigned int row = u / (FCOLS / 4);
        unsigned int c4 = u % (FCOLS / 4);
        *(f32x4*)(enc + (size_t)row * K + c4 * 4) = z;
    }
}

// ---- main: barrier-free direct-L2 MFMA sweep; all 8 waves carry fill stores
//      for cols [FCOLS, K); rolling-threshold candidate gate. ----
template<int E2T>
__global__ __launch_bounds__(THREADS, 4) void main_kernel(
        const float* __restrict__ X, const float* __restrict__ E,
        const unsigned short* __restrict__ e1t, const float* __restrict__ e2t,
        const float* __restrict__ enorm, float* __restrict__ out,
        float* __restrict__ partials) {
    __shared__ unsigned long long cand[CAND_CAP];   // 16 KB
    __shared__ unsigned long long best[BM];
    __shared__ unsigned int rmin[BM];
    __shared__ float red[THREADS];                  // 2 KB
    __shared__ int candn;

    const int t = threadIdx.x;
    const int wid = t >> 6, l = t & 63;
    const int l31 = l & 31, lh = l >> 5;
    const int rowbase = blockIdx.x * BM;

    float* qout = out;
    float* enc = out + (size_t)N * D;
    float* idxout = enc + (size_t)N * K;

    if (t < BM) { rmin[t] = RMIN_INIT; best[t] = ~0ull; }
    if (t == 0) candn = 0;
    __syncthreads();

    // A fragments: bf16(x) for the block's 32 rows (all waves same rows)
    short8 afr[8];
    {
        const int row = rowbase + l31;
#pragma unroll
        for (int ks = 0; ks < 8; ++ks) {
            const float* xp = X + (size_t)row * D + ks * 16 + lh * 8;
            f32x4 v0 = *(const f32x4*)xp;
            f32x4 v1 = *(const f32x4*)(xp + 4);
            short8 a;
            a[0] = (short)f2bf(v0[0]); a[1] = (short)f2bf(v0[1]);
            a[2] = (short)f2bf(v0[2]); a[3] = (short)f2bf(v0[3]);
            a[4] = (short)f2bf(v1[0]); a[5] = (short)f2bf(v1[1]);
            a[6] = (short)f2bf(v1[2]); a[7] = (short)f2bf(v1[3]);
            afr[ks] = a;
        }
    }

    const f32x4 z = {0.f, 0.f, 0.f, 0.f};
    float thrv[16];
#pragma unroll
    for (int r = 0; r < 16; ++r) thrv[r] = __uint_as_float(0x7F800000u); // +inf

    for (int ti = 0; ti < TILES; ++ti) {
        const int c = ti * 256 + wid * 32 + l31;    // this lane's codebook col

        // ---- loads FIRST (older than the fill stores -> stores stay in flight) ----
        short8 bf[8];
        const unsigned short* bp = e1t + (size_t)c * D + lh * 8;
#pragma unroll
        for (int ks = 0; ks < 8; ++ks)
            bf[ks] = *(const short8*)(bp + ks * 16);
        const float en = enorm[c];
        asm volatile("" ::: "memory");   // compiler fence: no store hoisting

        // ---- fill share: 2x 1KB units per step, cols [FCOLS, K), rows wid*4.. ----
        if (ti < 24) {
#pragma unroll
            for (int s = 0; s < 2; ++s) {
                const int j = ti * 2 + s;            // 0..47
                const int rl = j / 12, kb = j % 12;  // 4 rows x 12 KB per wave
                __builtin_nontemporal_store(z,
                    (f32x4*)(enc + (size_t)(rowbase + wid * 4 + rl) * K + FCOLS + kb * 256 + l * 4));
            }
        }

        // ---- MFMA (waits only its older loads; the 2 stores keep flying) ----
        f32x16 acc;
#pragma unroll
        for (int r = 0; r < 16; ++r) acc[r] = 0.f;
#pragma unroll
        for (int ks = 0; ks < 8; ++ks)
            acc = __builtin_amdgcn_mfma_f32_32x32x16_bf16(afr[ks], bf[ks], acc, 0, 0, 0);
#pragma unroll
        for (int r = 0; r < 16; ++r)
            acc[r] = fmaf(-2.f, acc[r], en);         // d~ = en - 2*sim

        // ---- gate ----
        if (ti == 0) {
            // one-time butterfly: wave-min per row-slot over this tile's 32 cols
#pragma unroll
            for (int r = 0; r < 16; ++r) thrv[r] = acc[r];
#pragma unroll
            for (int m = 1; m <= 16; m <<= 1)
#pragma unroll
                for (int r = 0; r < 16; ++r)
                    thrv[r] = fminf(thrv[r], __shfl_xor(thrv[r], m, 64));
#pragma unroll
            for (int r = 0; r < 16; ++r) {
                const int ro = (r & 3) + 8 * (r >> 2) + 4 * lh;
                if (acc[r] < thrv[r] + DELTA) {
                    int ci = atomicAdd(&candn, 1);
                    if (ci < CAND_CAP)
                        cand[ci] = ((unsigned long long)fsort(acc[r]) << 32) |
                                   ((unsigned long long)ro << 13) | (unsigned)c;
                }
                if (l31 == 0) atomicMin(&rmin[ro], fsort(thrv[r]));
            }
        } else {
            // rolling threshold: refresh from rmin (stale-safe), gate, rare atomics
#pragma unroll
            for (int q = 0; q < 4; ++q) {
                uint4 rv = *(const uint4*)&rmin[8 * q + 4 * lh];
                thrv[4 * q + 0] = funsort(rv.x);
                thrv[4 * q + 1] = funsort(rv.y);
                thrv[4 * q + 2] = funsort(rv.z);
                thrv[4 * q + 3] = funsort(rv.w);
            }
#pragma unroll
            for (int r = 0; r < 16; ++r) {
                const int ro = (r & 3) + 8 * (r >> 2) + 4 * lh;
                if (acc[r] < thrv[r] + DELTA) {
                    int ci = atomicAdd(&candn, 1);
                    if (ci < CAND_CAP)
                        cand[ci] = ((unsigned long long)fsort(acc[r]) << 32) |
                                   ((unsigned long long)ro << 13) | (unsigned)c;
                    if (acc[r] < thrv[r])
                        atomicMin(&rmin[ro], fsort(acc[r]));
                }
            }
        }
    }

    __syncthreads();   // FULL drain: fill stores complete; rmin/cand final

    // ---- exact f32 verification of surviving candidates ----
    {
        int n = candn; if (n > CAND_CAP) n = CAND_CAP;
        for (int i = wid; i < n; i += 8) {     // one wave per candidate
            const unsigned long long e = cand[i];
            const float dta = funsort((unsigned int)(e >> 32));
            const int ro = (int)((e >> 13) & 63u);
            const int col = (int)(e & 8191u);
            if (dta < funsort(rmin[ro]) + DELTA) {
                const int row = rowbase + ro;
                float x0 = X[(size_t)row * D + l];
                float x1 = X[(size_t)row * D + 64 + l];
                float e0, e1;
                if (E2T) {
                    e0 = e2t[(size_t)col * D + l];
                    e1 = e2t[(size_t)col * D + 64 + l];
                } else {
                    e0 = E[(size_t)l * K + col];
                    e1 = E[(size_t)(l + 64) * K + col];
                }
                float s = x0 * e0 + x1 * e1;
#pragma unroll
                for (int m = 1; m <= 32; m <<= 1) s += __shfl_xor(s, m, 64);
                if (l == 0) {
                    float dtx = enorm[col] - 2.f * s;
                    atomicMin(&best[ro],
                        ((unsigned long long)fsort(dtx) << 32) | (unsigned)col);
                }
            }
        }
    }
    __syncthreads();

    // ---- outputs: indices, one-hot scatter, quantized, loss partial ----
    if (t < BM) {
        const int k = (int)(best[t] & 8191ull);
        idxout[rowbase + t] = (float)k;
        enc[(size_t)(rowbase + t) * K + k] = 1.0f;
    }

    const int rr = t >> 4, sL = t & 15;     // 16 threads/row, 8 floats each
    const int row = rowbase + rr;
    const int kb = (int)(best[rr] & 8191ull);
    float part = 0.f;
#pragma unroll
    for (int j = 0; j < 2; ++j) {
        const int d0 = sL * 8 + 4 * j;
        f32x4 xv = *(const f32x4*)(X + (size_t)row * D + d0);
        f32x4 ev;
        if (E2T) {
            ev = *(const f32x4*)(e2t + (size_t)kb * D + d0);
        } else {
#pragma unroll
            for (int u = 0; u < 4; ++u) ev[u] = E[(size_t)(d0 + u) * K + kb];
        }
        f32x4 qv;
#pragma unroll
        for (int u = 0; u < 4; ++u) {
            float df = ev[u] - xv[u];
            qv[u] = xv[u] + df;
            part += df * df;
        }
        *(f32x4*)(qout + (size_t)row * D + d0) = qv;
    }
    red[t] = part;
    __syncthreads();
#pragma unroll
    for (int off = THREADS / 2; off > 0; off >>= 1) {
        if (t < off) red[t] += red[t + off];
        __syncthreads();
    }
    if (t == 0) partials[blockIdx.x] = red[0];
}

__global__ __launch_bounds__(256) void loss_kernel(const float* __restrict__ partials,
                                                   float* __restrict__ out) {
    __shared__ float red[256];
    const int t = threadIdx.x;
    red[t] = partials[t] + partials[t + 256];
    __syncthreads();
    for (int off = 128; off > 0; off >>= 1) {
        if (t < off) red[t] += red[t + off];
        __syncthreads();
    }
    if (t == 0) {
        float mean = red[0] / (float)((size_t)N * D);
        out[(size_t)N * D + (size_t)N * K + N] = mean + 0.25f * mean;
    }
}

extern "C" void kernel_launch(void* const* d_in, const int* in_sizes, int n_in,
                              void* d_out, int out_size, void* d_ws, size_t ws_size,
                              hipStream_t stream) {
    const float* X = (const float*)d_in[0];
    const float* E = (const float*)d_in[1];
    float* out = (float*)d_out;
    float* enc = out + (size_t)N * D;
    char* ws = (char*)d_ws;

    const size_t E1T_B = (size_t)K * D * 2;          // 2 MB
    const size_t E2T_B = (size_t)K * D * 4;          // 4 MB
    const bool use_e2t = ws_size >= E1T_B + E2T_B + 64 * 1024;

    unsigned short* e1t = (unsigned short*)ws;
    float* e2t; float* enorm; float* partials;
    if (use_e2t) {
        e2t = (float*)(ws + E1T_B);
        enorm = (float*)(ws + E1T_B + E2T_B);
        partials = enorm + K;
    } else {
        e2t = nullptr;
        enorm = (float*)(ws + E1T_B);
        partials = enorm + K;
    }

    hipLaunchKernelGGL(prep_kernel, dim3(K / 32), dim3(256), 0, stream,
                       E, e1t, e2t, enorm);
    hipLaunchKernelGGL(fill_kernel, dim3(4096), dim3(256), 0, stream, enc);
    if (use_e2t)
        hipLaunchKernelGGL((main_kernel<1>), dim3(N / BM), dim3(THREADS), 0, stream,
                           X, E, e1t, e2t, enorm, out, partials);
    else
        hipLaunchKernelGGL((main_kernel<0>), dim3(N / BM), dim3(THREADS), 0, stream,
                           X, E, e1t, e2t, enorm, out, partials);
    hipLaunchKernelGGL(loss_kernel, dim3(1), dim3(256), 0, stream, partials, out);
}